// Round 17
// baseline (299.573 us; speedup 1.0000x reference)
//
#include <hip/hip_runtime.h>
#include <hip/hip_bf16.h>

#define B_ 4
#define T_ 8192
#define N_ 64
#define F_ 16
#define O_ 32

typedef _Float16 half8_t __attribute__((ext_vector_type(8)));
typedef _Float16 half4_t __attribute__((ext_vector_type(4)));
typedef float float4_t __attribute__((ext_vector_type(4)));

// ---------------- workspace layout (byte offsets) ----------------
// A1G  : 0         (8192 f32)      [b][2048] = [A1(1024) | G(1024)]
// Wft  : 98304     (786432 B f16)  fragment-swizzled: [b][og][kk][lane][8]
// P    : 884736    (8 MiB f32)     [b][tile][2048] partials (256 tiles/b)
// xh   : 18874368  (~64 MiB f16)   [b][T+2][1024]  f16 x copy, zero halo rows
#define WS_A1G  0
#define WS_WFT  98304
#define WS_P    884736
#define WS_XH   18874368

#define TB_ 32   // t-rows per kA2 block

// ---------------------------------------------------------------------------
// Kernel A2 (fused stream+reduce, batched loads — R14-measured config).
//   accA[n,f] = sum_{t in tile} W1[t] * x[b,t,n,f]
//   accG[n,f] = sum_{t in tile} W2[f,t] * (sum_f' W3[f'] * x[b,t,n,f'])
// grid = B * (T/32) = 1024 blocks of 256 threads.
__global__ __launch_bounds__(256) void kA2(const float* __restrict__ x,
                                           const float* __restrict__ W1,
                                           const float* __restrict__ W2,
                                           const float* __restrict__ W3,
                                           float* __restrict__ P,
                                           _Float16* __restrict__ xh) {
    __shared__ float w2s[16][TB_ + 1];
    __shared__ float w1s[TB_];
    const int b    = blockIdx.x >> 8;        // 256 tiles per b
    const int tile = blockIdx.x & 255;
    const int t0   = tile * TB_;
    const int tid  = threadIdx.x;
    const int fq   = tid & 3;                // f-quarter (4 floats)

    for (int i = tid; i < 16 * TB_; i += 256) {
        const int f = i >> 5, r = i & 31;
        w2s[f][r] = W2[f * T_ + t0 + r];
    }
    if (tid < TB_) w1s[tid] = W1[t0 + tid];
    __syncthreads();

    float w3v[4];
#pragma unroll
    for (int j = 0; j < 4; ++j) w3v[j] = W3[fq * 4 + j];

    const float* xbase = x + ((size_t)b * T_ + t0) * 1024 + tid * 4;
    _Float16* xhb = xh + ((size_t)b * (T_ + 2) + t0 + 1) * 1024 + tid * 4;
    float4_t accA = {0.f, 0.f, 0.f, 0.f};
    float4_t accG = {0.f, 0.f, 0.f, 0.f};

#pragma unroll
    for (int rb = 0; rb < TB_; rb += 8) {
        float4_t xv[8];
#pragma unroll
        for (int i = 0; i < 8; ++i)
            xv[i] = *(const float4_t*)(xbase + (size_t)(rb + i) * 1024);

        float v[8];
#pragma unroll
        for (int i = 0; i < 8; ++i)
            v[i] = xv[i][0] * w3v[0] + xv[i][1] * w3v[1]
                 + xv[i][2] * w3v[2] + xv[i][3] * w3v[3];
#pragma unroll
        for (int i = 0; i < 8; ++i) v[i] += __shfl_xor(v[i], 1);
#pragma unroll
        for (int i = 0; i < 8; ++i) v[i] += __shfl_xor(v[i], 2);
#pragma unroll
        for (int i = 0; i < 8; ++i) {
            const float w1r = w1s[rb + i];
#pragma unroll
            for (int j = 0; j < 4; ++j) {
                accA[j] += w1r * xv[i][j];
                accG[j] += w2s[fq * 4 + j][rb + i] * v[i];
            }
        }

#pragma unroll
        for (int i = 0; i < 8; ++i) {
            half4_t hv;
            hv[0] = (_Float16)xv[i][0]; hv[1] = (_Float16)xv[i][1];
            hv[2] = (_Float16)xv[i][2]; hv[3] = (_Float16)xv[i][3];
            *(half4_t*)(xhb + (size_t)(rb + i) * 1024) = hv;
        }
    }

    // zero halo rows (ws is poisoned each call)
    {
        half4_t z = {(_Float16)0.f, (_Float16)0.f, (_Float16)0.f, (_Float16)0.f};
        if (tile == 0)
            *(half4_t*)(xh + (size_t)b * (T_ + 2) * 1024 + tid * 4) = z;
        if (tile == 255)
            *(half4_t*)(xh + ((size_t)b * (T_ + 2) + T_ + 1) * 1024 + tid * 4) = z;
    }

    float* pb = P + (size_t)blockIdx.x * 2048 + tid * 4;
    *(float4_t*)pb          = accA;
    *(float4_t*)(pb + 1024) = accG;
}

// ---------------------------------------------------------------------------
// Kernel R: reduce the 256 per-tile partials -> A1G[b][2048].
// grid = B*64 = 256 blocks (R14-measured config).
__global__ __launch_bounds__(256) void kR(const float* __restrict__ P,
                                          float* __restrict__ A1G) {
    const int b   = blockIdx.x >> 6;
    const int seg = blockIdx.x & 63;
    const int tid = threadIdx.x;
    const int o4  = tid & 7;
    const int g   = tid >> 3;

    const float* base = P + (size_t)b * 256 * 2048 + seg * 32 + o4 * 4;
    float4_t s = {0.f, 0.f, 0.f, 0.f};
#pragma unroll
    for (int tt = 0; tt < 8; ++tt) {
        float4_t v = *(const float4_t*)(base + (size_t)(g * 8 + tt) * 2048);
        s += v;
    }

    __shared__ float4_t red[32][8];
    red[g][o4] = s;
    __syncthreads();
    if (tid < 8) {
        float4_t t = {0.f, 0.f, 0.f, 0.f};
#pragma unroll
        for (int gg = 0; gg < 32; ++gg) t += red[gg][tid];
        *(float4_t*)(A1G + (size_t)b * 2048 + seg * 32 + tid * 4) = t;
    }
}

// ---------------------------------------------------------------------------
// Kernel CD (merged kC+kD): each block redundantly computes its b's attention
// matrix in LDS (cheap, fully parallel), then folds conv weights for its o:
//   sig = sigmoid(A1 G^T + bs); s0 = Vs sig; S = softmax_r(s0); ssc = S*diag
//   Wft[swz(b,o,e)] = sum_n conv_w[o, n*16+f, k] * ssc[m][n]
// Removes the kC dispatch + the Ssc global round-trip.
// LDS overlay: attn phase uses [a1|g|vs|sig|redmx|redsm] (43.5 KB); after the
// final softmax barrier all of it is dead, so ssc+cw overlay the same buffer.
// grid = B*O = 128 blocks.
__global__ __launch_bounds__(256) void kCD(const float* __restrict__ A1G,
                                           const float* __restrict__ bs,
                                           const float* __restrict__ Vs,
                                           const float* __restrict__ adj,
                                           const float* __restrict__ conv_w,
                                           _Float16* __restrict__ Wft) {
    const int b = blockIdx.x >> 5, o = blockIdx.x & 31;
    __shared__ float smem[10880];
    float* a1  = smem;            // [64][17] = 1088
    float* g   = smem + 1088;     // [64][17] = 1088
    float* vs  = smem + 2176;     // [64][64] = 4096
    float* sig = smem + 6272;     // [64][64] = 4096
    float* rmx = smem + 10368;    // [4][64]  = 256
    float* rsm = smem + 10624;    // [4][64]  = 256
    const int tid = threadIdx.x;

    for (int i = tid; i < 1024; i += 256) {
        a1[(i >> 4) * 17 + (i & 15)] = A1G[b * 2048 + i];
        g [(i >> 4) * 17 + (i & 15)] = A1G[b * 2048 + 1024 + i];
    }
    for (int i = tid; i < 4096; i += 256) vs[i] = Vs[i];
    __syncthreads();

    // sig = sigmoid(A1 G^T + bs)
#pragma unroll
    for (int i = 0; i < 16; ++i) {
        const int e = tid + 256 * i, r = e >> 6, c = e & 63;
        float p = 0.f;
#pragma unroll
        for (int f = 0; f < 16; ++f) p += a1[r * 17 + f] * g[c * 17 + f];
        p += bs[e];
        sig[r * 64 + c] = 1.f / (1.f + __expf(-p));
    }
    __syncthreads();

    const int gw = tid >> 6;
    const int c  = tid & 63;
    const int r0 = gw * 16;

    float sc_[64];
#pragma unroll
    for (int m = 0; m < 64; ++m) sc_[m] = sig[m * 64 + c];

    float acc[16];
#pragma unroll
    for (int rl = 0; rl < 16; ++rl) {
        const float4_t* vr = (const float4_t*)&vs[(r0 + rl) * 64];
        float sA = 0.f, sB = 0.f, sC = 0.f, sD = 0.f;
#pragma unroll
        for (int m4 = 0; m4 < 4; ++m4) {
            float4_t v0 = vr[m4];
            float4_t v1 = vr[m4 + 4];
            float4_t v2 = vr[m4 + 8];
            float4_t v3 = vr[m4 + 12];
#pragma unroll
            for (int j = 0; j < 4; ++j) {
                sA += v0[j] * sc_[m4 * 4 + j];
                sB += v1[j] * sc_[16 + m4 * 4 + j];
                sC += v2[j] * sc_[32 + m4 * 4 + j];
                sD += v3[j] * sc_[48 + m4 * 4 + j];
            }
        }
        acc[rl] = (sA + sB) + (sC + sD);
    }

    float pmax = -1e30f;
#pragma unroll
    for (int rl = 0; rl < 16; ++rl) pmax = fmaxf(pmax, acc[rl]);
    rmx[gw * 64 + c] = pmax;
    __syncthreads();
    const float mx = fmaxf(fmaxf(rmx[c], rmx[64 + c]),
                           fmaxf(rmx[128 + c], rmx[192 + c]));

    float psum = 0.f;
#pragma unroll
    for (int rl = 0; rl < 16; ++rl) {
        acc[rl] = __expf(acc[rl] - mx);
        psum += acc[rl];
    }
    rsm[gw * 64 + c] = psum;
    __syncthreads();                      // after this, ALL vs/sig reads done
    const float sum = (rsm[c] + rsm[64 + c]) + (rsm[128 + c] + rsm[192 + c]);
    const float scl = adj[c * 64 + c] / sum;

    // -------- overlay phase: ssc (attn result) + cw over the dead buffer ----
    float* ssc = smem;            // [64][64] = 4096 floats (over a1|g|vs head)
    float* cw  = smem + 4096;     // [3072]          (over vs tail | sig head)
#pragma unroll
    for (int rl = 0; rl < 16; ++rl)
        ssc[(r0 + rl) * 64 + c] = acc[rl] * scl;
    for (int i = tid; i < 3072; i += 256) cw[i] = conv_w[o * 3072 + i];
    __syncthreads();

    const size_t obase = (size_t)(b * 2 + (o >> 4)) * 49152 + (size_t)(o & 15) * 8;
#pragma unroll
    for (int i = 0; i < 12; ++i) {
        const int e = tid + 256 * i;
        const int k = e >> 10, rem = e & 1023, m = rem >> 4, f = rem & 15;
        float s = 0.f;
#pragma unroll
        for (int n = 0; n < 64; ++n) s += cw[(n * 16 + f) * 3 + k] * ssc[m * 64 + n];
        const size_t wi = obase + (size_t)(e >> 5) * 512
                        + (size_t)(((e >> 3) & 3) * 16) * 8 + (e & 7);
        Wft[wi] = (_Float16)s;
    }
}

// ---------------------------------------------------------------------------
// Kernel E16: out[b,t,o] = sum_K xh[b, pad(t+K/1024-1), K%1024] * Wft_swz
// ONE acc per wave (16t x 16o) -> grid doubles to 1024 blocks = 16 waves/CU
// (2x the latency hiding of the 2-acc version). Channel-major, taps innermost.
// grid = B * (T/32) = 1024 blocks.
__global__ __launch_bounds__(256) void kE16(const _Float16* __restrict__ xh,
                                            const _Float16* __restrict__ Wft,
                                            float* __restrict__ out) {
    const int b    = blockIdx.x >> 8;
    const int tile = blockIdx.x & 255;
    const int wave = threadIdx.x >> 6;
    const int lane = threadIdx.x & 63;
    const int q = lane >> 4, l = lane & 15;
    const int tq = wave >> 1, oh = wave & 1;
    const int t0 = tile * 32 + tq * 16;

    const _Float16* wb = Wft + (size_t)(b * 2 + oh) * 49152 + lane * 8;
    // padded row index for tap kc: (t0 + l + kc - 1) + 1 = t0 + l + kc
    const _Float16* xb = xh + ((size_t)b * (T_ + 2) + (t0 + l)) * 1024 + q * 8;

    float4_t acc = {0.f, 0.f, 0.f, 0.f};

#pragma unroll 4
    for (int c = 0; c < 32; ++c) {
        const int c0 = c * 32;                   // channel block base (halfs)
#pragma unroll
        for (int kc = 0; kc < 3; ++kc) {
            const int kk = kc * 32 + c;          // Wft fragment index

            half8_t af = *(const half8_t*)(xb + (size_t)kc * 1024 + c0);
            half8_t bf = *(const half8_t*)(wb + (size_t)kk * 512);
            acc = __builtin_amdgcn_mfma_f32_16x16x32_f16(af, bf, acc, 0, 0, 0);
        }
    }

#pragma unroll
    for (int rg = 0; rg < 4; ++rg) {
        const int t = t0 + q * 4 + rg;
        out[((size_t)b * T_ + t) * 32 + oh * 16 + l] = acc[rg];
    }
}

// ---------------------------------------------------------------------------
extern "C" void kernel_launch(void* const* d_in, const int* in_sizes, int n_in,
                              void* d_out, int out_size, void* d_ws, size_t ws_size,
                              hipStream_t stream) {
    const float* x      = (const float*)d_in[0];
    const float* adj    = (const float*)d_in[1];
    const float* W1     = (const float*)d_in[2];
    const float* W2     = (const float*)d_in[3];
    const float* W3     = (const float*)d_in[4];
    const float* bs     = (const float*)d_in[5];
    const float* Vs     = (const float*)d_in[6];
    const float* conv_w = (const float*)d_in[7];
    float* out = (float*)d_out;

    char* ws = (char*)d_ws;
    float*    A1G = (float*)(ws + WS_A1G);
    _Float16* Wft = (_Float16*)(ws + WS_WFT);
    float*    P   = (float*)(ws + WS_P);
    _Float16* xh  = (_Float16*)(ws + WS_XH);

    kA2 <<<B_ * (T_ / TB_), 256, 0, stream>>>(x, W1, W2, W3, P, xh);
    kR  <<<B_ * 64,         256, 0, stream>>>(P, A1G);
    kCD <<<B_ * O_,         256, 0, stream>>>(A1G, bs, Vs, adj, conv_w, Wft);
    kE16<<<B_ * (T_ / 32),  256, 0, stream>>>(xh, Wft, out);
}

// Round 20
// 278.933 us; speedup vs baseline: 1.0740x; 1.0740x over previous
//
#include <hip/hip_runtime.h>
#include <hip/hip_bf16.h>

#define B_ 4
#define T_ 8192
#define N_ 64
#define F_ 16
#define O_ 32

typedef _Float16 half8_t __attribute__((ext_vector_type(8)));
typedef _Float16 half4_t __attribute__((ext_vector_type(4)));
typedef float float4_t __attribute__((ext_vector_type(4)));

// ---------------- workspace layout (byte offsets) ----------------
// A1G  : 0         (8192 f32)      [b][2048] = [A1(1024) | G(1024)]
// Wft  : 98304     (786432 B f16)  fragment-swizzled: [b][og][kk][lane][8]
// P    : 884736    (8 MiB f32)     [b][tile][2048] partials (256 tiles/b)
// xh   : 18874368  (~64 MiB f16)   [b][T+2][1024]  f16 x copy, zero halo rows
#define WS_A1G  0
#define WS_WFT  98304
#define WS_P    884736
#define WS_XH   18874368

#define TB_ 32   // t-rows per kA2 block

// ---------------------------------------------------------------------------
// Kernel A2 (fused stream+reduce, batch-4 loads): thread = (n, fq).
// R17 measured batch-8 at VGPR=184 / occupancy 9.8% — register pressure
// collapsed the wave count and nullified the deeper load window. Batch 4
// halves live state (xv[4]+v[4]) for ~2x occupancy at 4 loads in flight.
//   accA[n,f] = sum_{t in tile} W1[t] * x[b,t,n,f]
//   accG[n,f] = sum_{t in tile} W2[f,t] * (sum_f' W3[f'] * x[b,t,n,f'])
// grid = B * (T/32) = 1024 blocks of 256 threads.
__global__ __launch_bounds__(256) void kA2(const float* __restrict__ x,
                                           const float* __restrict__ W1,
                                           const float* __restrict__ W2,
                                           const float* __restrict__ W3,
                                           float* __restrict__ P,
                                           _Float16* __restrict__ xh) {
    __shared__ float w2s[16][TB_ + 1];
    __shared__ float w1s[TB_];
    const int b    = blockIdx.x >> 8;        // 256 tiles per b
    const int tile = blockIdx.x & 255;
    const int t0   = tile * TB_;
    const int tid  = threadIdx.x;
    const int fq   = tid & 3;                // f-quarter (4 floats)

    for (int i = tid; i < 16 * TB_; i += 256) {
        const int f = i >> 5, r = i & 31;
        w2s[f][r] = W2[f * T_ + t0 + r];
    }
    if (tid < TB_) w1s[tid] = W1[t0 + tid];
    __syncthreads();

    float w3v[4];
#pragma unroll
    for (int j = 0; j < 4; ++j) w3v[j] = W3[fq * 4 + j];

    const float* xbase = x + ((size_t)b * T_ + t0) * 1024 + tid * 4;
    _Float16* xhb = xh + ((size_t)b * (T_ + 2) + t0 + 1) * 1024 + tid * 4;
    float4_t accA = {0.f, 0.f, 0.f, 0.f};
    float4_t accG = {0.f, 0.f, 0.f, 0.f};

#pragma unroll
    for (int rb = 0; rb < TB_; rb += 4) {
        // phase 1: 4 independent loads issued back-to-back
        float4_t xv[4];
#pragma unroll
        for (int i = 0; i < 4; ++i)
            xv[i] = *(const float4_t*)(xbase + (size_t)(rb + i) * 1024);

        // phase 2: compute (4 independent shfl chains overlap)
        float v[4];
#pragma unroll
        for (int i = 0; i < 4; ++i)
            v[i] = xv[i][0] * w3v[0] + xv[i][1] * w3v[1]
                 + xv[i][2] * w3v[2] + xv[i][3] * w3v[3];
#pragma unroll
        for (int i = 0; i < 4; ++i) v[i] += __shfl_xor(v[i], 1);
#pragma unroll
        for (int i = 0; i < 4; ++i) v[i] += __shfl_xor(v[i], 2);
#pragma unroll
        for (int i = 0; i < 4; ++i) {
            const float w1r = w1s[rb + i];
#pragma unroll
            for (int j = 0; j < 4; ++j) {
                accA[j] += w1r * xv[i][j];
                accG[j] += w2s[fq * 4 + j][rb + i] * v[i];
            }
        }

        // phase 3: 4 f16 stores
#pragma unroll
        for (int i = 0; i < 4; ++i) {
            half4_t hv;
            hv[0] = (_Float16)xv[i][0]; hv[1] = (_Float16)xv[i][1];
            hv[2] = (_Float16)xv[i][2]; hv[3] = (_Float16)xv[i][3];
            *(half4_t*)(xhb + (size_t)(rb + i) * 1024) = hv;
        }
    }

    // zero halo rows (ws is poisoned each call)
    {
        half4_t z = {(_Float16)0.f, (_Float16)0.f, (_Float16)0.f, (_Float16)0.f};
        if (tile == 0)
            *(half4_t*)(xh + (size_t)b * (T_ + 2) * 1024 + tid * 4) = z;
        if (tile == 255)
            *(half4_t*)(xh + ((size_t)b * (T_ + 2) + T_ + 1) * 1024 + tid * 4) = z;
    }

    float* pb = P + (size_t)blockIdx.x * 2048 + tid * 4;
    *(float4_t*)pb          = accA;
    *(float4_t*)(pb + 1024) = accG;
}

// ---------------------------------------------------------------------------
// Kernel R: reduce the 256 per-tile partials -> A1G[b][2048].
// grid = B*64 = 256 blocks (R14-measured config).
__global__ __launch_bounds__(256) void kR(const float* __restrict__ P,
                                          float* __restrict__ A1G) {
    const int b   = blockIdx.x >> 6;
    const int seg = blockIdx.x & 63;
    const int tid = threadIdx.x;
    const int o4  = tid & 7;
    const int g   = tid >> 3;

    const float* base = P + (size_t)b * 256 * 2048 + seg * 32 + o4 * 4;
    float4_t s = {0.f, 0.f, 0.f, 0.f};
#pragma unroll
    for (int tt = 0; tt < 8; ++tt) {
        float4_t v = *(const float4_t*)(base + (size_t)(g * 8 + tt) * 2048);
        s += v;
    }

    __shared__ float4_t red[32][8];
    red[g][o4] = s;
    __syncthreads();
    if (tid < 8) {
        float4_t t = {0.f, 0.f, 0.f, 0.f};
#pragma unroll
        for (int gg = 0; gg < 32; ++gg) t += red[gg][tid];
        *(float4_t*)(A1G + (size_t)b * 2048 + seg * 32 + tid * 4) = t;
    }
}

// ---------------------------------------------------------------------------
// Kernel CD (merged kC+kD, R17-verified correct): each block redundantly
// computes its b's attention matrix in LDS, then folds conv weights for its o.
// grid = B*O = 128 blocks.
__global__ __launch_bounds__(256) void kCD(const float* __restrict__ A1G,
                                           const float* __restrict__ bs,
                                           const float* __restrict__ Vs,
                                           const float* __restrict__ adj,
                                           const float* __restrict__ conv_w,
                                           _Float16* __restrict__ Wft) {
    const int b = blockIdx.x >> 5, o = blockIdx.x & 31;
    __shared__ float smem[10880];
    float* a1  = smem;            // [64][17] = 1088
    float* g   = smem + 1088;     // [64][17] = 1088
    float* vs  = smem + 2176;     // [64][64] = 4096
    float* sig = smem + 6272;     // [64][64] = 4096
    float* rmx = smem + 10368;    // [4][64]  = 256
    float* rsm = smem + 10624;    // [4][64]  = 256
    const int tid = threadIdx.x;

    for (int i = tid; i < 1024; i += 256) {
        a1[(i >> 4) * 17 + (i & 15)] = A1G[b * 2048 + i];
        g [(i >> 4) * 17 + (i & 15)] = A1G[b * 2048 + 1024 + i];
    }
    for (int i = tid; i < 4096; i += 256) vs[i] = Vs[i];
    __syncthreads();

#pragma unroll
    for (int i = 0; i < 16; ++i) {
        const int e = tid + 256 * i, r = e >> 6, c = e & 63;
        float p = 0.f;
#pragma unroll
        for (int f = 0; f < 16; ++f) p += a1[r * 17 + f] * g[c * 17 + f];
        p += bs[e];
        sig[r * 64 + c] = 1.f / (1.f + __expf(-p));
    }
    __syncthreads();

    const int gw = tid >> 6;
    const int c  = tid & 63;
    const int r0 = gw * 16;

    float sc_[64];
#pragma unroll
    for (int m = 0; m < 64; ++m) sc_[m] = sig[m * 64 + c];

    float acc[16];
#pragma unroll
    for (int rl = 0; rl < 16; ++rl) {
        const float4_t* vr = (const float4_t*)&vs[(r0 + rl) * 64];
        float sA = 0.f, sB = 0.f, sC = 0.f, sD = 0.f;
#pragma unroll
        for (int m4 = 0; m4 < 4; ++m4) {
            float4_t v0 = vr[m4];
            float4_t v1 = vr[m4 + 4];
            float4_t v2 = vr[m4 + 8];
            float4_t v3 = vr[m4 + 12];
#pragma unroll
            for (int j = 0; j < 4; ++j) {
                sA += v0[j] * sc_[m4 * 4 + j];
                sB += v1[j] * sc_[16 + m4 * 4 + j];
                sC += v2[j] * sc_[32 + m4 * 4 + j];
                sD += v3[j] * sc_[48 + m4 * 4 + j];
            }
        }
        acc[rl] = (sA + sB) + (sC + sD);
    }

    float pmax = -1e30f;
#pragma unroll
    for (int rl = 0; rl < 16; ++rl) pmax = fmaxf(pmax, acc[rl]);
    rmx[gw * 64 + c] = pmax;
    __syncthreads();
    const float mx = fmaxf(fmaxf(rmx[c], rmx[64 + c]),
                           fmaxf(rmx[128 + c], rmx[192 + c]));

    float psum = 0.f;
#pragma unroll
    for (int rl = 0; rl < 16; ++rl) {
        acc[rl] = __expf(acc[rl] - mx);
        psum += acc[rl];
    }
    rsm[gw * 64 + c] = psum;
    __syncthreads();                      // after this, ALL vs/sig reads done
    const float sum = (rsm[c] + rsm[64 + c]) + (rsm[128 + c] + rsm[192 + c]);
    const float scl = adj[c * 64 + c] / sum;

    // -------- overlay phase: ssc (attn result) + cw over the dead buffer ----
    float* ssc = smem;            // [64][64] = 4096 floats
    float* cw  = smem + 4096;     // [3072]
#pragma unroll
    for (int rl = 0; rl < 16; ++rl)
        ssc[(r0 + rl) * 64 + c] = acc[rl] * scl;
    for (int i = tid; i < 3072; i += 256) cw[i] = conv_w[o * 3072 + i];
    __syncthreads();

    const size_t obase = (size_t)(b * 2 + (o >> 4)) * 49152 + (size_t)(o & 15) * 8;
#pragma unroll
    for (int i = 0; i < 12; ++i) {
        const int e = tid + 256 * i;
        const int k = e >> 10, rem = e & 1023, m = rem >> 4, f = rem & 15;
        float s = 0.f;
#pragma unroll
        for (int n = 0; n < 64; ++n) s += cw[(n * 16 + f) * 3 + k] * ssc[m * 64 + n];
        const size_t wi = obase + (size_t)(e >> 5) * 512
                        + (size_t)(((e >> 3) & 3) * 16) * 8 + (e & 7);
        Wft[wi] = (_Float16)s;
    }
}

// ---------------------------------------------------------------------------
// Kernel E16 (REVERTED to R14 2-acc config): out[b,t,o] = conv via MFMA.
// Wave tile 16t x 32o: each af gather feeds TWO MFMAs (the 1-acc variant
// doubled total gather instructions and regressed — R17 post-mortem).
// Channel-major, taps innermost. grid = B * (T/64) = 512 blocks.
__global__ __launch_bounds__(256) void kE16(const _Float16* __restrict__ xh,
                                            const _Float16* __restrict__ Wft,
                                            float* __restrict__ out) {
    const int b    = blockIdx.x >> 7;
    const int tile = blockIdx.x & 127;
    const int wave = threadIdx.x >> 6;
    const int lane = threadIdx.x & 63;
    const int q = lane >> 4, l = lane & 15;
    const int t0 = tile * 64 + wave * 16;

    const _Float16* wb0 = Wft + (size_t)(b * 2)     * 49152 + lane * 8;  // og=0
    const _Float16* wb1 = Wft + (size_t)(b * 2 + 1) * 49152 + lane * 8;  // og=1
    // padded row index for tap kc: (t0 + l + kc - 1) + 1 = t0 + l + kc
    const _Float16* xb = xh + ((size_t)b * (T_ + 2) + (t0 + l)) * 1024 + q * 8;

    float4_t acc0 = {0.f, 0.f, 0.f, 0.f};
    float4_t acc1 = {0.f, 0.f, 0.f, 0.f};

#pragma unroll 2
    for (int c = 0; c < 32; ++c) {
        const int c0 = c * 32;                   // channel block base (halfs)
#pragma unroll
        for (int kc = 0; kc < 3; ++kc) {
            const int kk = kc * 32 + c;          // Wft fragment index

            half8_t af  = *(const half8_t*)(xb + (size_t)kc * 1024 + c0);
            half8_t bf0 = *(const half8_t*)(wb0 + (size_t)kk * 512);
            half8_t bf1 = *(const half8_t*)(wb1 + (size_t)kk * 512);

            acc0 = __builtin_amdgcn_mfma_f32_16x16x32_f16(af, bf0, acc0, 0, 0, 0);
            acc1 = __builtin_amdgcn_mfma_f32_16x16x32_f16(af, bf1, acc1, 0, 0, 0);
        }
    }

#pragma unroll
    for (int rg = 0; rg < 4; ++rg) {
        const int t = t0 + q * 4 + rg;
        float* op = out + ((size_t)b * T_ + t) * 32;
        op[l]      = acc0[rg];
        op[16 + l] = acc1[rg];
    }
}

// ---------------------------------------------------------------------------
extern "C" void kernel_launch(void* const* d_in, const int* in_sizes, int n_in,
                              void* d_out, int out_size, void* d_ws, size_t ws_size,
                              hipStream_t stream) {
    const float* x      = (const float*)d_in[0];
    const float* adj    = (const float*)d_in[1];
    const float* W1     = (const float*)d_in[2];
    const float* W2     = (const float*)d_in[3];
    const float* W3     = (const float*)d_in[4];
    const float* bs     = (const float*)d_in[5];
    const float* Vs     = (const float*)d_in[6];
    const float* conv_w = (const float*)d_in[7];
    float* out = (float*)d_out;

    char* ws = (char*)d_ws;
    float*    A1G = (float*)(ws + WS_A1G);
    _Float16* Wft = (_Float16*)(ws + WS_WFT);
    float*    P   = (float*)(ws + WS_P);
    _Float16* xh  = (_Float16*)(ws + WS_XH);

    kA2 <<<B_ * (T_ / TB_), 256, 0, stream>>>(x, W1, W2, W3, P, xh);
    kR  <<<B_ * 64,         256, 0, stream>>>(P, A1G);
    kCD <<<B_ * O_,         256, 0, stream>>>(A1G, bs, Vs, adj, conv_w, Wft);
    kE16<<<B_ * (T_ / 64),  256, 0, stream>>>(xh, Wft, out);
}